// Round 7
// baseline (102.738 us; speedup 1.0000x reference)
//
#include <hip/hip_runtime.h>
#include <cstddef>
#include <cstdint>

#define B_ 32
#define C_ 64
#define HW_ 16384
#define HW4_ 4096
#define PC_ 3
#define NCHK_ 32
#define INV_N_ (1.0f/49152.0f)

typedef __attribute__((ext_vector_type(8))) short bf16x8;
typedef __attribute__((ext_vector_type(4))) short s16x4;
typedef __attribute__((ext_vector_type(4))) float f32x4;

// ---- output layout (float indices) ----
#define OUT_DM_   ((size_t)B_*PC_*HW_)      // predicts first: 1572864
#define OUT_IDX_  (OUT_DM_ + (size_t)B_*64)
#define OUT_LOSS_ (OUT_IDX_ + B_)
#define OUT_DIST_ (OUT_LOSS_ + B_)

// ---- workspace layout (float indices) ----
#define SLOT_     2768
#define NUSED_    2755
#define REDU_OFF_ ((size_t)64)
#define PART_OFF_ (REDU_OFF_ + (size_t)B_*SLOT_)

// split f32 -> hi/lo bf16 (RNE each), hi+lo covers ~16 mantissa bits
__device__ __forceinline__ void split2(float x, short& hs, short& ls) {
    unsigned u = __float_as_uint(x);
    unsigned hr = (u + 0x7FFFu + ((u >> 16) & 1u)) >> 16;
    float hf = __uint_as_float(hr << 16);
    float r = x - hf;                       // exact
    unsigned v = __float_as_uint(r);
    unsigned lo = (v + 0x7FFFu + ((v >> 16) & 1u)) >> 16;
    hs = (short)hr; ls = (short)lo;
}

// 3-pass split-bf16 product accumulate: C += Ah*Bh + Ah*Bl + Al*Bh
// (Al*Bl term ~2^-34 relative -- negligible)
__device__ __forceinline__ f32x4 mm3(bf16x8 ah, bf16x8 al, bf16x8 bh, bf16x8 bl, f32x4 c) {
    c = __builtin_amdgcn_mfma_f32_16x16x32_bf16(ah, bh, c, 0, 0, 0);
    c = __builtin_amdgcn_mfma_f32_16x16x32_bf16(ah, bl, c, 0, 0, 0);
    c = __builtin_amdgcn_mfma_f32_16x16x32_bf16(al, bh, c, 0, 0, 0);
    return c;
}

// =====================================================================
// K1: per (b, chunk of 512 px): M = sum f f^T (10 upper 16x16 tiles),
// v[pc] = sum f*r, rsq = sum r^2 via split-bf16 MFMA.
// Coalesced global->reg with TWO staging register sets (loads issued ~2
// phases before use); split once at staging; XOR-swizzled LDS planes;
// double-buffered LDS, 1 barrier/tile. Wave->tile map (no cross-wave
// reduce): w0:{M00,M01,M11,v0} w1:{M22,M23,M33,v2} w2:{M02,M12,v1}
// w3:{M03,M13,v3,rr}.
// =====================================================================
__global__ __launch_bounds__(256, 4)
void k1_stats(const float* __restrict__ feat, const float* __restrict__ target,
              const float* __restrict__ pred, float* __restrict__ ws) {
    const int b = blockIdx.x >> 5, chunk = blockIdx.x & 31;
    const int t = threadIdx.x, wv = t >> 6, lane = t & 63;
    const int lr = lane & 15, lg = lane >> 4;
    const int row16 = t >> 4, px4 = t & 15;

    __shared__ __align__(16) short fH[2][64][64];   // 16 KB
    __shared__ __align__(16) short fL[2][64][64];   // 16 KB
    __shared__ __align__(16) short rH[2][3][64];
    __shared__ __align__(16) short rL[2][3][64];

    f32x4 acc[4];
#pragma unroll
    for (int i = 0; i < 4; ++i) acc[i] = (f32x4){0.f, 0.f, 0.f, 0.f};

    const float4* feat4 = (const float4*)feat;
    const float4* pred4 = (const float4*)pred;
    const float4* targ4 = (const float4*)target;
    const size_t cbase4 = (size_t)chunk * 128;      // 512 px = 128 float4
    const size_t fbase  = (size_t)b * 64 * HW4_ + (size_t)row16 * HW4_ + cbase4 + px4;
    const size_t rbase  = ((size_t)b * 3 + row16) * HW4_ + cbase4 + px4;  // valid t<48

    float4 sfA[4], sfB[4];
    float4 spA = {0,0,0,0}, stA = {0,0,0,0}, spB = {0,0,0,0}, stB = {0,0,0,0};

#define LOADA_(tl) {                                                         \
    _Pragma("unroll")                                                        \
    for (int i = 0; i < 4; ++i)                                              \
        sfA[i] = feat4[fbase + (size_t)(16 * i) * HW4_ + (tl) * 16];         \
    if (t < 48) { spA = pred4[rbase + (tl) * 16];                            \
                  stA = targ4[rbase + (tl) * 16]; } }
#define LOADB_(tl) {                                                         \
    _Pragma("unroll")                                                        \
    for (int i = 0; i < 4; ++i)                                              \
        sfB[i] = feat4[fbase + (size_t)(16 * i) * HW4_ + (tl) * 16];         \
    if (t < 48) { spB = pred4[rbase + (tl) * 16];                            \
                  stB = targ4[rbase + (tl) * 16]; } }

#define WRITE_IMPL_(nb, sf, sp, st) {                                        \
    _Pragma("unroll")                                                        \
    for (int i = 0; i < 4; ++i) {                                            \
        const int ch = row16 + 16 * i;                                       \
        const int so = (px4 * 4) ^ ((ch & 7) << 3);                          \
        const float fx[4] = {sf[i].x, sf[i].y, sf[i].z, sf[i].w};            \
        s16x4 hv, lv;                                                        \
        _Pragma("unroll")                                                    \
        for (int j = 0; j < 4; ++j) {                                        \
            short h_, l_; split2(fx[j], h_, l_); hv[j] = h_; lv[j] = l_; }   \
        *(s16x4*)&fH[nb][ch][so] = hv;                                       \
        *(s16x4*)&fL[nb][ch][so] = lv;                                       \
    }                                                                        \
    if (t < 48) {                                                            \
        const int so = (px4 * 4) ^ (row16 << 3);                             \
        const float rx[4] = {sp.x - st.x, sp.y - st.y, sp.z - st.z, sp.w - st.w}; \
        s16x4 hv, lv;                                                        \
        _Pragma("unroll")                                                    \
        for (int j = 0; j < 4; ++j) {                                        \
            short h_, l_; split2(rx[j], h_, l_); hv[j] = h_; lv[j] = l_; }   \
        *(s16x4*)&rH[nb][row16][so] = hv;                                    \
        *(s16x4*)&rL[nb][row16][so] = lv;                                    \
    } }
#define WRITEA_(nb) WRITE_IMPL_(nb, sfA, spA, stA)
#define WRITEB_(nb) WRITE_IMPL_(nb, sfB, spB, stB)

#define FRAG_(dh, dl, nb, ch_) {                                             \
    const int off_ = ko ^ (((ch_) & 7) << 3);                                \
    dh = *(const bf16x8*)&fH[nb][(ch_)][off_];                               \
    dl = *(const bf16x8*)&fL[nb][(ch_)][off_]; }
#define RFRAG_(dh, dl, nb) {                                                 \
    dh = (bf16x8){0,0,0,0,0,0,0,0}; dl = (bf16x8){0,0,0,0,0,0,0,0};          \
    if (lr < 3) {                                                            \
        const int off_ = ko ^ (lr << 3);                                     \
        dh = *(const bf16x8*)&rH[nb][lr][off_];                              \
        dl = *(const bf16x8*)&rL[nb][lr][off_]; } }

#define COMPUTE_(nb) {                                                       \
    _Pragma("unroll")                                                        \
    for (int ks = 0; ks < 2; ++ks) {                                         \
        const int ko = ks * 32 + lg * 8;                                     \
        if (wv == 0) {                                                       \
            bf16x8 a0h,a0l,a1h,a1l,rh,rl2;                                   \
            FRAG_(a0h,a0l,nb,lr); FRAG_(a1h,a1l,nb,16+lr);                   \
            RFRAG_(rh,rl2,nb);                                               \
            acc[0] = mm3(a0h,a0l,a0h,a0l,acc[0]);   /* M00 */                \
            acc[1] = mm3(a0h,a0l,a1h,a1l,acc[1]);   /* M01 */                \
            acc[2] = mm3(a1h,a1l,a1h,a1l,acc[2]);   /* M11 */                \
            acc[3] = mm3(rh,rl2,a0h,a0l,acc[3]);    /* v0  */                \
        } else if (wv == 1) {                                                \
            bf16x8 a2h,a2l,a3h,a3l,rh,rl2;                                   \
            FRAG_(a2h,a2l,nb,32+lr); FRAG_(a3h,a3l,nb,48+lr);                 \
            RFRAG_(rh,rl2,nb);                                               \
            acc[0] = mm3(a2h,a2l,a2h,a2l,acc[0]);   /* M22 */                \
            acc[1] = mm3(a2h,a2l,a3h,a3l,acc[1]);   /* M23 */                \
            acc[2] = mm3(a3h,a3l,a3h,a3l,acc[2]);   /* M33 */                \
            acc[3] = mm3(rh,rl2,a2h,a2l,acc[3]);    /* v2  */                \
        } else if (wv == 2) {                                                \
            bf16x8 a0h,a0l,a1h,a1l,a2h,a2l,rh,rl2;                           \
            FRAG_(a0h,a0l,nb,lr); FRAG_(a1h,a1l,nb,16+lr);                   \
            FRAG_(a2h,a2l,nb,32+lr); RFRAG_(rh,rl2,nb);                      \
            acc[0] = mm3(a0h,a0l,a2h,a2l,acc[0]);   /* M02 */                \
            acc[1] = mm3(a1h,a1l,a2h,a2l,acc[1]);   /* M12 */                \
            acc[2] = mm3(rh,rl2,a1h,a1l,acc[2]);    /* v1  */                \
        } else {                                                             \
            bf16x8 a0h,a0l,a1h,a1l,a3h,a3l,rh,rl2;                           \
            FRAG_(a0h,a0l,nb,lr); FRAG_(a1h,a1l,nb,16+lr);                   \
            FRAG_(a3h,a3l,nb,48+lr); RFRAG_(rh,rl2,nb);                      \
            acc[0] = mm3(a0h,a0l,a3h,a3l,acc[0]);   /* M03 */                \
            acc[1] = mm3(a1h,a1l,a3h,a3l,acc[1]);   /* M13 */                \
            acc[2] = mm3(rh,rl2,a3h,a3l,acc[2]);    /* v3  */                \
            acc[3] = mm3(rh,rl2,rh,rl2,acc[3]);     /* rr  */                \
        }                                                                    \
    } }

    // ---- prologue: tile0 staged+written; tile1 (A) and tile2 (B) in flight
    LOADA_(0);
    WRITEA_(0);
    LOADA_(1);
    LOADB_(2);
    __syncthreads();

    // ---- 8-tile pipeline, loads ~2 phases ahead ----
    COMPUTE_(0);  WRITEA_(1); LOADA_(3); __syncthreads();   // t=0
    COMPUTE_(1);  WRITEB_(0); LOADB_(4); __syncthreads();   // t=1
    COMPUTE_(0);  WRITEA_(1); LOADA_(5); __syncthreads();   // t=2
    COMPUTE_(1);  WRITEB_(0); LOADB_(6); __syncthreads();   // t=3
    COMPUTE_(0);  WRITEA_(1); LOADA_(7); __syncthreads();   // t=4
    COMPUTE_(1);  WRITEB_(0); __syncthreads();              // t=5
    COMPUTE_(0);  WRITEA_(1); __syncthreads();              // t=6
    COMPUTE_(1);                                            // t=7

#undef LOADA_
#undef LOADB_
#undef WRITE_IMPL_
#undef WRITEA_
#undef WRITEB_
#undef FRAG_
#undef RFRAG_
#undef COMPUTE_

    // ---- epilogue: wave-private coalesced stores ----
    // tile-major order tt: (0,0),(0,1),(0,2),(0,3),(1,1),(1,2),(1,3),(2,2),(2,3),(3,3)
    float* P = ws + PART_OFF_ + (size_t)blockIdx.x * SLOT_;
    if (wv == 0) {
#pragma unroll
        for (int q = 0; q < 4; ++q) {
            P[0 * 256 + q * 64 + lane] = acc[0][q];   // M00
            P[1 * 256 + q * 64 + lane] = acc[1][q];   // M01
            P[4 * 256 + q * 64 + lane] = acc[2][q];   // M11
        }
        if (lg == 0) {
            P[2560 + 0 * 64 + 0 + lr] = acc[3][0];    // v0
            P[2560 + 1 * 64 + 0 + lr] = acc[3][1];
            P[2560 + 2 * 64 + 0 + lr] = acc[3][2];
        }
    } else if (wv == 1) {
#pragma unroll
        for (int q = 0; q < 4; ++q) {
            P[7 * 256 + q * 64 + lane] = acc[0][q];   // M22
            P[8 * 256 + q * 64 + lane] = acc[1][q];   // M23
            P[9 * 256 + q * 64 + lane] = acc[2][q];   // M33
        }
        if (lg == 0) {
            P[2560 + 0 * 64 + 32 + lr] = acc[3][0];   // v2
            P[2560 + 1 * 64 + 32 + lr] = acc[3][1];
            P[2560 + 2 * 64 + 32 + lr] = acc[3][2];
        }
    } else if (wv == 2) {
#pragma unroll
        for (int q = 0; q < 4; ++q) {
            P[2 * 256 + q * 64 + lane] = acc[0][q];   // M02
            P[5 * 256 + q * 64 + lane] = acc[1][q];   // M12
        }
        if (lg == 0) {
            P[2560 + 0 * 64 + 16 + lr] = acc[2][0];   // v1
            P[2560 + 1 * 64 + 16 + lr] = acc[2][1];
            P[2560 + 2 * 64 + 16 + lr] = acc[2][2];
        }
    } else {
#pragma unroll
        for (int q = 0; q < 4; ++q) {
            P[3 * 256 + q * 64 + lane] = acc[0][q];   // M03
            P[6 * 256 + q * 64 + lane] = acc[1][q];   // M13
        }
        if (lg == 0) {
            P[2560 + 0 * 64 + 48 + lr] = acc[2][0];   // v3
            P[2560 + 1 * 64 + 48 + lr] = acc[2][1];
            P[2560 + 2 * 64 + 48 + lr] = acc[2][2];
        }
        if (lane == 0) P[2752] = acc[3][0];           // rr diag
        if (lane == 1) P[2753] = acc[3][1];
        if (lane == 2) P[2754] = acc[3][2];
    }
}

// =====================================================================
// K2a: grid-wide reduce of 32 partial slots per b (352 blocks)
// =====================================================================
__global__ __launch_bounds__(256)
void k2a_reduce(float* __restrict__ ws) {
    const int b = blockIdx.x / 11, blk = blockIdx.x % 11;
    const int pos = blk * 256 + threadIdx.x;
    if (pos >= NUSED_) return;
    const float* P = ws + PART_OFF_ + (size_t)b * NCHK_ * SLOT_ + pos;
    float s = 0.f;
#pragma unroll
    for (int c = 0; c < NCHK_; ++c) s += P[(size_t)c * SLOT_];
    ws[REDU_OFF_ + (size_t)b * SLOT_ + pos] = s;
}

// =====================================================================
// K2b: rebuild M (mirror), dist_k = (w^T M w + 2 w.v + rsq)/N; argmin.
// =====================================================================
__global__ __launch_bounds__(256)
void k2b_dist(const float* __restrict__ weight, float* __restrict__ ws,
              float* __restrict__ dout) {
    const int b = blockIdx.x, t = threadIdx.x;
    __shared__ __align__(16) float Ml[64][64];
    __shared__ __align__(16) float vl[192];
    __shared__ float red[3][64];
    __shared__ float rl;

    const float* R = ws + REDU_OFF_ + (size_t)b * SLOT_;
    const int TI[10] = {0,0,0,0,1,1,1,2,2,3};
    const int TJ[10] = {0,1,2,3,1,2,3,2,3,3};
    {
        const int q = t >> 6, lg2 = (t >> 4) & 3, lr2 = t & 15;
        const int r16 = lg2 * 4 + q, c16 = lr2;
#pragma unroll
        for (int r = 0; r < 10; ++r) {
            const int gi = TI[r], gj = TJ[r];
            const float val = R[r * 256 + t];
            Ml[gi * 16 + r16][gj * 16 + c16] = val;
            if (gi != gj) Ml[gj * 16 + c16][gi * 16 + r16] = val;
        }
    }
    if (t < 192) vl[t] = R[2560 + t];
    if (t == 0) rl = R[2752] + R[2753] + R[2754];
    __syncthreads();

    if (t < 192) {
        const int k = t & 63, pc = t >> 6;
        const float4* wr = (const float4*)(weight + (size_t)(3 * k + pc) * 64);
        float4 w[16];
#pragma unroll
        for (int j = 0; j < 16; ++j) w[j] = wr[j];
        float s = 0.f;
#pragma unroll 2
        for (int i4 = 0; i4 < 16; ++i4) {
            const float wi[4] = {w[i4].x, w[i4].y, w[i4].z, w[i4].w};
#pragma unroll
            for (int ii = 0; ii < 4; ++ii) {
                const int i = i4 * 4 + ii;
                const float4* Mr = (const float4*)&Ml[i][0];
                float4 ya = make_float4(0.f, 0.f, 0.f, 0.f);
#pragma unroll
                for (int j = 0; j < 16; ++j) {
                    ya.x += Mr[j].x * w[j].x; ya.y += Mr[j].y * w[j].y;
                    ya.z += Mr[j].z * w[j].z; ya.w += Mr[j].w * w[j].w;
                }
                s += wi[ii] * (ya.x + ya.y + ya.z + ya.w);
            }
        }
        const float4* vl4 = (const float4*)&vl[pc * 64];
        float4 sv = make_float4(0.f, 0.f, 0.f, 0.f);
#pragma unroll
        for (int j = 0; j < 16; ++j) {
            sv.x += vl4[j].x * w[j].x; sv.y += vl4[j].y * w[j].y;
            sv.z += vl4[j].z * w[j].z; sv.w += vl4[j].w * w[j].w;
        }
        red[pc][k] = s + 2.f * (sv.x + sv.y + sv.z + sv.w);
    }
    __syncthreads();
    if (t < 64) {
        float d = (red[0][t] + red[1][t] + red[2][t] + rl) * INV_N_;
        dout[OUT_DM_ + (size_t)b * 64 + t] = d;
        int idx = t;
#pragma unroll
        for (int off = 32; off >= 1; off >>= 1) {
            const float od = __shfl_xor(d, off);
            const int   oi = __shfl_xor(idx, off);
            if (od < d || (od == d && oi < idx)) { d = od; idx = oi; }
        }
        if (t == 0) {
            ((int*)ws)[b] = idx;
            dout[OUT_IDX_  + b] = (float)idx;
            dout[OUT_LOSS_ + b] = d;   // loss == distances mathematically
            dout[OUT_DIST_ + b] = d;
        }
    }
}

// =====================================================================
// K4: winning candidate only. 2048 blocks; 4 waves split the channel dim
// (16 each) and combine via LDS.
// =====================================================================
__global__ __launch_bounds__(256)
void k4_pred(const float* __restrict__ feat, const float* __restrict__ predl,
             const float* __restrict__ weight, const float* __restrict__ ws,
             float* __restrict__ dout) {
    const int b = blockIdx.x >> 6, sb = blockIdx.x & 63;
    const int t = threadIdx.x, lane = t & 63, wv = t >> 6;
    __shared__ float wl[PC_][64];
    __shared__ __align__(16) float4 red[3][PC_][64];
    const int kbest = ((const int*)ws)[b];
    if (t < 192) wl[t >> 6][t & 63] = weight[(size_t)(kbest * 3 + (t >> 6)) * 64 + (t & 63)];
    __syncthreads();
    const int hw4 = sb * 64 + lane;
    const float4* f4 = (const float4*)feat;
    const size_t base4 = (size_t)b * C_ * HW4_ + hw4;
    float4 a0 = {0,0,0,0}, a1 = {0,0,0,0}, a2 = {0,0,0,0};
#pragma unroll
    for (int i = 0; i < 16; ++i) {
        const int c = wv * 16 + i;
        const float4 f = f4[base4 + (size_t)c * HW4_];
        const float w0 = wl[0][c], w1 = wl[1][c], w2 = wl[2][c];
        a0.x += f.x*w0; a0.y += f.y*w0; a0.z += f.z*w0; a0.w += f.w*w0;
        a1.x += f.x*w1; a1.y += f.y*w1; a1.z += f.z*w1; a1.w += f.w*w1;
        a2.x += f.x*w2; a2.y += f.y*w2; a2.z += f.z*w2; a2.w += f.w*w2;
    }
    const float4* p4 = (const float4*)predl;
    const size_t ob = (size_t)b * PC_ * HW4_ + hw4;
    float4 pl0, pl1, pl2;
    if (wv == 0) { pl0 = p4[ob]; pl1 = p4[ob + 4096]; pl2 = p4[ob + 8192]; }
    else { red[wv-1][0][lane] = a0; red[wv-1][1][lane] = a1; red[wv-1][2][lane] = a2; }
    __syncthreads();
    if (wv == 0) {
#pragma unroll
        for (int w = 0; w < 3; ++w) {
            const float4 x0 = red[w][0][lane], x1 = red[w][1][lane], x2 = red[w][2][lane];
            a0.x += x0.x; a0.y += x0.y; a0.z += x0.z; a0.w += x0.w;
            a1.x += x1.x; a1.y += x1.y; a1.z += x1.z; a1.w += x1.w;
            a2.x += x2.x; a2.y += x2.y; a2.z += x2.z; a2.w += x2.w;
        }
        a0.x += pl0.x; a0.y += pl0.y; a0.z += pl0.z; a0.w += pl0.w;
        a1.x += pl1.x; a1.y += pl1.y; a1.z += pl1.z; a1.w += pl1.w;
        a2.x += pl2.x; a2.y += pl2.y; a2.z += pl2.z; a2.w += pl2.w;
        float4* o4 = (float4*)dout;
        o4[ob]        = a0;
        o4[ob + 4096] = a1;
        o4[ob + 8192] = a2;
    }
}

extern "C" void kernel_launch(void* const* d_in, const int* in_sizes, int n_in,
                              void* d_out, int out_size, void* d_ws, size_t ws_size,
                              hipStream_t stream) {
    const float* feat   = (const float*)d_in[0];
    const float* target = (const float*)d_in[1];
    const float* predl  = (const float*)d_in[2];
    const float* weight = (const float*)d_in[3];
    float* out = (float*)d_out;
    float* wsf = (float*)d_ws;
    (void)ws_size;

    hipLaunchKernelGGL(k1_stats, dim3(B_ * NCHK_), dim3(256), 0, stream,
                       feat, target, predl, wsf);
    hipLaunchKernelGGL(k2a_reduce, dim3(B_ * 11), dim3(256), 0, stream, wsf);
    hipLaunchKernelGGL(k2b_dist, dim3(B_), dim3(256), 0, stream,
                       weight, wsf, out);
    hipLaunchKernelGGL(k4_pred, dim3(B_ * 64), dim3(256), 0, stream,
                       feat, predl, weight, wsf, out);
}